// Round 24
// baseline (342.086 us; speedup 1.0000x reference)
//
#include <hip/hip_runtime.h>
#include <math.h>

#define G_ 512
#define N_ 512
#define NN_ (G_*N_)
#define EG_ 8192
#define EGP 8704      // padded edge capacity per graph (even-padded bins)
#define CIN_ 128
#define HID_ 32
#define K_ 20
#define LAT_ 65
#define NSTRIPE 4
#define SW 8          // channels per stripe
#define HP 513        // hd2 row pitch (doubles); slot 512 = sentinel -0.0

// relative tie window: ~1.5 ulp of fp32 (2^-23 = 1.19e-7)
#define EPS_REL 1.8e-7f

// ---------------- CSR build v4: histogram-balanced nperm (O(N)) ------------
__global__ __launch_bounds__(512) void csr2_kernel(const int* __restrict__ src,
                                                   const int* __restrict__ dst,
                                                   unsigned short* __restrict__ srcl,
                                                   int* __restrict__ gstart,
                                                   unsigned short* __restrict__ nperm,
                                                   double* __restrict__ disd) {
    __shared__ int cnt[N_];
    __shared__ int startv[N_];
    __shared__ int tmpv[N_];
    __shared__ int cursor[N_];
    __shared__ int hcur[128];
    __shared__ unsigned short binE[EGP];   // 17 KB, 0xFFFF = hole
    int g = blockIdx.x, tid = threadIdx.x;
    const int* ds = dst + (size_t)g * EG_;
    const int* ss = src + (size_t)g * EG_;
    int nb = g * N_;

    cnt[tid] = 0;
    if (tid < 128) hcur[tid] = 0;
    for (int i = tid; i < EGP; i += 512) binE[i] = 0xFFFF;
    __syncthreads();
    for (int e = tid; e < EG_; e += 512) atomicAdd(&cnt[ds[e] - nb], 1);
    __syncthreads();

    int mydeg = cnt[tid];
    int db = mydeg < 127 ? mydeg : 127;
    atomicAdd(&hcur[db], 1);
    __syncthreads();
    if (tid == 0) {
        int run = 0;
        for (int d = 0; d < 128; ++d) { int v = hcur[d]; hcur[d] = run; run += v; }
    }
    __syncthreads();
    {
        int slot = atomicAdd(&hcur[db], 1);
        nperm[g * N_ + slot] = (unsigned short)tid;
    }

    int pc = (mydeg + 1) & ~1;            // even-padded bin size
    startv[tid] = pc;
    __syncthreads();
    for (int off = 1; off < N_; off <<= 1) {
        tmpv[tid] = startv[tid] + (tid >= off ? startv[tid - off] : 0);
        __syncthreads();
        startv[tid] = tmpv[tid];
        __syncthreads();
    }

    int excl = startv[tid] - pc;
    cursor[tid] = excl;
    gstart[g * (N_ + 1) + tid] = excl;
    if (tid == 511) gstart[g * (N_ + 1) + N_] = startv[511];
    disd[nb + tid] = 1.0 / sqrt((double)(mydeg + 1));
    __syncthreads();

    for (int e = tid; e < EG_; e += 512) {
        int d = ds[e] - nb;
        int slot = atomicAdd(&cursor[d], 1);
        binE[slot] = (unsigned short)e;
    }
    __syncthreads();

    {   // canonicalize own bin: insertion sort by edge id (original order)
        int n = mydeg;
        for (int i = 1; i < n; ++i) {
            unsigned short key = binE[excl + i];
            int j = i - 1;
            while (j >= 0 && binE[excl + j] > key) {
                binE[excl + j + 1] = binE[excl + j];
                --j;
            }
            binE[excl + j + 1] = key;
        }
    }
    __syncthreads();

    for (int i = tid; i < EGP; i += 512) {
        unsigned short e = binE[i];
        srcl[(size_t)g * EGP + i] =
            (e == 0xFFFF) ? (unsigned short)N_ : (unsigned short)(ss[e] - nb);
    }
}

// ---------------- fused GCN layer: in-block mm + aggregation ---------------
// Thread s computes its node's h-row slice with the IDENTICAL c-ascending
// fp64 fma chain the split mm used, scales by dis[s] into hd2, then the
// paired-edge gather phase runs unchanged. sWd staged fp64 (fp32->fp64 is
// exact: staging-time conversion == per-use). grid = (NSTRIPE, G).
template <int CI>
__global__ __launch_bounds__(512) void agg_mm_kernel(
        const float* __restrict__ xin,    // [NN][CI]
        const float* __restrict__ W,      // [CI][32]
        const unsigned short* __restrict__ srcl,
        const int* __restrict__ gstart,
        const unsigned short* __restrict__ nperm,
        const double* __restrict__ disd,
        const float* __restrict__ bias,
        float* __restrict__ xoutf) {
    __shared__ double hd2[SW * HP];            // 32.8 KB
    __shared__ unsigned short ssrc[EGP];       // 17.4 KB
    __shared__ unsigned short sstart[N_ + 2];  // 1 KB
    __shared__ double sWd[CI * SW];            // fp64 W slice: CI=128: 8 KB
    int st = blockIdx.x, g = blockIdx.y, tid = threadIdx.x;
    size_t nbase = (size_t)g * N_;

    for (int i = tid; i < EGP; i += 512) ssrc[i] = srcl[(size_t)g * EGP + i];
    for (int i = tid; i <= N_; i += 512) sstart[i] = (unsigned short)gstart[g * (N_ + 1) + i];
    for (int i = tid; i < CI * SW; i += 512) {
        int c = i >> 3, oc = i & 7;
        sWd[i] = (double)W[c * HID_ + st * SW + oc];
    }
    __syncthreads();

    const double* dg = disd + nbase;
    {   // in-block mm: node s = tid; chunked x row loads, c-ascending chain
        int s = tid;
        const float4* xr4 = (const float4*)(xin + (nbase + s) * CI);
        double a[SW];
#pragma unroll
        for (int oc = 0; oc < SW; ++oc) a[oc] = 0.0;
#pragma unroll
        for (int c0 = 0; c0 < CI; c0 += 16) {
            float4 v0 = xr4[c0 / 4 + 0];
            float4 v1 = xr4[c0 / 4 + 1];
            float4 v2 = xr4[c0 / 4 + 2];
            float4 v3 = xr4[c0 / 4 + 3];
            float xc[16] = { v0.x, v0.y, v0.z, v0.w, v1.x, v1.y, v1.z, v1.w,
                             v2.x, v2.y, v2.z, v2.w, v3.x, v3.y, v3.z, v3.w };
#pragma unroll
            for (int cc = 0; cc < 16; ++cc) {
                double xv = (double)xc[cc];
                const double* wrow = &sWd[(c0 + cc) * SW];
#pragma unroll
                for (int oc = 0; oc < SW; ++oc)
                    a[oc] = fma(xv, wrow[oc], a[oc]);
            }
        }
        double ds = dg[s];
#pragma unroll
        for (int oc = 0; oc < SW; ++oc)
            hd2[oc * HP + s] = a[oc] * ds;
    }
    if (tid < SW) hd2[tid * HP + N_] = -0.0;   // sentinel
    __syncthreads();

    int oc = tid & 7, grp = tid >> 3;   // 64 node-groups x 8 channels
    const double* hrow = hd2 + oc * HP;
    const unsigned int* ssrc32 = (const unsigned int*)ssrc;
    double b = (double)bias[st * SW + oc];

    int nn[8], e0h[8], e1h[8];
    double a[8];
    int mx = 0;
#pragma unroll
    for (int j = 0; j < 8; ++j) {
        int n = nperm[g * N_ + grp * 8 + j];
        nn[j] = n;
        e0h[j] = sstart[n] >> 1;
        e1h[j] = sstart[n + 1] >> 1;
        a[j] = 0.0;
        int d = e1h[j] - e0h[j];
        mx = d > mx ? d : mx;
    }
    for (int t = 0; t < mx; ++t) {
#pragma unroll
        for (int j = 0; j < 8; ++j) {
            int idx = e0h[j] + t;
            if (idx < e1h[j]) {
                unsigned int pr = ssrc32[idx];
                a[j] += hrow[pr & 0xFFFFu];
                a[j] += hrow[pr >> 16];
            }
        }
    }
#pragma unroll
    for (int j = 0; j < 8; ++j) {
        int n = nn[j];
        double dn = dg[n];
        double v = a[j] * dn + hrow[n] * dn + b;
        xoutf[(nbase + n) * HID_ + st * SW + oc] = tanhf((float)v);
    }
}

// ---------------- fused layer-3 + head (one block per graph, 512 thr) ------
__global__ __launch_bounds__(512) void gcn3_head_kernel(
        const float* __restrict__ xin,      // x2f
        const float* __restrict__ W2,
        const float* __restrict__ b2,
        const unsigned short* __restrict__ srcl,
        const int* __restrict__ gstart,
        const double* __restrict__ disd,
        const float* __restrict__ x1,
        const float* __restrict__ x2,
        const float* __restrict__ c1w, const float* __restrict__ c1b,
        const float* __restrict__ c2w, const float* __restrict__ c2b,
        const float* __restrict__ l1w, const float* __restrict__ l1b,
        const float* __restrict__ l2w, const float* __restrict__ l2b,
        float* __restrict__ out) {
    __shared__ double h1[N_ + 1];
    __shared__ unsigned short ssrc[EGP];
    __shared__ int sstart[N_ + 1];
    __shared__ double sdis[N_ + 1];
    __shared__ float sv[N_];
    __shared__ int   topk[K_];
    __shared__ float pooled[K_][LAT_];
    __shared__ float c1[16][K_];
    __shared__ float mp[16][10];
    __shared__ float c2s[32 * 6];
    __shared__ float l1s[128];
    int g = blockIdx.x, tid = threadIdx.x;
    size_t nbase = (size_t)g * N_;

    for (int i = tid; i < EGP; i += 512) ssrc[i] = srcl[(size_t)g * EGP + i];
    for (int i = tid; i <= N_; i += 512) sstart[i] = gstart[g * (N_ + 1) + i];
    if (tid == 0) { h1[N_] = -0.0; sdis[N_] = 1.0; }   // sentinel term: -0.0
    if (tid < K_) topk[tid] = tid;                      // fallback init
    int n = tid;
    {
        double a = 0.0;
#pragma unroll
        for (int c = 0; c < HID_; ++c)
            a = fma((double)xin[(nbase + n) * HID_ + c], (double)W2[c], a);
        h1[n] = a;
        sdis[n] = disd[nbase + n];
    }
    __syncthreads();

    {
        int e0 = sstart[n], e1 = sstart[n + 1];
        double a = 0.0;
        for (int e = e0; e < e1; ++e) {
            int s = ssrc[e];
            a += h1[s] * sdis[s];
        }
        double dn = sdis[n];
        double v = a * dn + h1[n] * dn * dn + (double)b2[0];
        sv[n] = (float)tanh(v);   // fp32 rank key AND feature value
    }
    __syncthreads();

    {
        float v = sv[n];
        int rank = 0;
        for (int j = 0; j < N_; ++j) {
            float u = sv[j];
            float mag = fmaxf(fabsf(u), fabsf(v));
            bool tie = fabsf(u - v) <= EPS_REL * mag;
            bool beats = tie ? (j < n) : (u > v);
            rank += beats;
        }
        if (rank < K_) topk[rank] = n;
    }
    __syncthreads();

    for (int i = tid; i < K_ * LAT_; i += 512) {
        int k = i / LAT_, c = i % LAT_;
        int node = topk[k];
        float f;
        if (c < HID_)            f = x1[(nbase + node) * HID_ + c];
        else if (c < 2 * HID_)   f = x2[(nbase + node) * HID_ + (c - HID_)];
        else                     f = sv[node];
        pooled[k][c] = f;
    }
    __syncthreads();

    for (int i = tid; i < 16 * K_; i += 512) {
        int o = i / K_, k = i % K_;
        float acc = c1b[o];
        for (int c = 0; c < LAT_; ++c) acc += pooled[k][c] * c1w[o * LAT_ + c];
        c1[o][k] = fmaxf(acc, 0.f);
    }
    __syncthreads();

    for (int i = tid; i < 160; i += 512) {
        int o = i / 10, t = i % 10;
        mp[o][t] = fmaxf(c1[o][2 * t], c1[o][2 * t + 1]);
    }
    __syncthreads();

    for (int i = tid; i < 192; i += 512) {
        int o = i / 6, t = i % 6;
        float acc = c2b[o];
        for (int ic = 0; ic < 16; ++ic)
#pragma unroll
            for (int j = 0; j < 5; ++j)
                acc += mp[ic][t + j] * c2w[(o * 16 + ic) * 5 + j];
        c2s[o * 6 + t] = fmaxf(acc, 0.f);
    }
    __syncthreads();

    for (int i = tid; i < 128; i += 512) {
        float acc = l1b[i];
        for (int c = 0; c < 192; ++c) acc += c2s[c] * l1w[c * 128 + i];
        l1s[i] = fmaxf(acc, 0.f);
    }
    __syncthreads();

    for (int i = tid; i < 2; i += 512) {
        float acc = l2b[i];
        for (int c = 0; c < 128; ++c) acc += l1s[c] * l2w[c * 2 + i];
        out[g * 2 + i] = acc;
    }
}

extern "C" void kernel_launch(void* const* d_in, const int* in_sizes, int n_in,
                              void* d_out, int out_size, void* d_ws, size_t ws_size,
                              hipStream_t stream) {
    const float* x   = (const float*)d_in[0];
    const int*   ei  = (const int*)d_in[1];
    const float* W0  = (const float*)d_in[3];
    const float* b0  = (const float*)d_in[4];
    const float* W1  = (const float*)d_in[5];
    const float* b1  = (const float*)d_in[6];
    const float* W2  = (const float*)d_in[7];
    const float* b2  = (const float*)d_in[8];
    const float* c1w = (const float*)d_in[9];
    const float* c1b = (const float*)d_in[10];
    const float* c2w = (const float*)d_in[11];
    const float* c2b = (const float*)d_in[12];
    const float* l1w = (const float*)d_in[13];
    const float* l1b = (const float*)d_in[14];
    const float* l2w = (const float*)d_in[15];
    const float* l2b = (const float*)d_in[16];

    const int* src = ei;
    const int* dst = ei + (size_t)G_ * EG_;

    char* wsb = (char*)d_ws;
    unsigned short* srcl = (unsigned short*)wsb; wsb += (size_t)G_ * EGP * 2;       // 8.5 MiB
    int* gstart = (int*)wsb;                     wsb += (size_t)G_ * (N_ + 1) * 4;  // 1 MiB
    unsigned short* nperm = (unsigned short*)wsb; wsb += (size_t)G_ * N_ * 2;       // 0.5 MiB
    double* disd = (double*)wsb;                 wsb += (size_t)NN_ * 8;            // 2 MiB
    float*  x1f  = (float*)wsb;                  wsb += (size_t)NN_ * HID_ * 4;     // 32 MiB
    float*  x2f  = (float*)wsb;                  wsb += (size_t)NN_ * HID_ * 4;     // 32 MiB

    dim3 agrid(NSTRIPE, G_);
    csr2_kernel<<<G_, 512, 0, stream>>>(src, dst, srcl, gstart, nperm, disd);
    agg_mm_kernel<CIN_><<<agrid, 512, 0, stream>>>(x, W0, srcl, gstart, nperm, disd, b0, x1f);
    agg_mm_kernel<HID_><<<agrid, 512, 0, stream>>>(x1f, W1, srcl, gstart, nperm, disd, b1, x2f);
    gcn3_head_kernel<<<G_, 512, 0, stream>>>(x2f, W2, b2, srcl, gstart, disd,
                                             x1f, x2f, c1w, c1b, c2w, c2b,
                                             l1w, l1b, l2w, l2b, (float*)d_out);
}

// Round 25
// 323.212 us; speedup vs baseline: 1.0584x; 1.0584x over previous
//
#include <hip/hip_runtime.h>
#include <math.h>

#define G_ 512
#define N_ 512
#define NN_ (G_*N_)
#define EG_ 8192
#define EGP 8704      // padded edge capacity per graph (even-padded bins)
#define CIN_ 128
#define HID_ 32
#define K_ 20
#define LAT_ 65
#define NSTRIPE 4
#define SW 8          // channels per stripe
#define HP 513        // hd2 row pitch (doubles); slot 512 = sentinel -0.0

// relative tie window: ~1.5 ulp of fp32 (2^-23 = 1.19e-7)
#define EPS_REL 1.8e-7f

// XCD-aware decode for stripe-parallel kernels: all 4 stripes of a graph get
// flat ids congruent mod 8 -> same XCD -> shared L2 for x1f/srcl/nperm.
__device__ __forceinline__ void decode_swz(int f, int& g, int& st) {
    int xcd = f & 7;
    int q = f >> 3;
    st = q & 3;
    g = xcd + 8 * (q >> 2);
}

// ---------------- CSR build v4: histogram-balanced nperm (O(N)) ------------
__global__ __launch_bounds__(512) void csr2_kernel(const int* __restrict__ src,
                                                   const int* __restrict__ dst,
                                                   unsigned short* __restrict__ srcl,
                                                   int* __restrict__ gstart,
                                                   unsigned short* __restrict__ nperm,
                                                   double* __restrict__ disd) {
    __shared__ int cnt[N_];
    __shared__ int startv[N_];
    __shared__ int tmpv[N_];
    __shared__ int cursor[N_];
    __shared__ int hcur[128];
    __shared__ unsigned short binE[EGP];   // 17 KB, 0xFFFF = hole
    int g = blockIdx.x, tid = threadIdx.x;
    const int* ds = dst + (size_t)g * EG_;
    const int* ss = src + (size_t)g * EG_;
    int nb = g * N_;

    cnt[tid] = 0;
    if (tid < 128) hcur[tid] = 0;
    for (int i = tid; i < EGP; i += 512) binE[i] = 0xFFFF;
    __syncthreads();
    for (int e = tid; e < EG_; e += 512) atomicAdd(&cnt[ds[e] - nb], 1);
    __syncthreads();

    int mydeg = cnt[tid];
    int db = mydeg < 127 ? mydeg : 127;
    atomicAdd(&hcur[db], 1);
    __syncthreads();
    if (tid == 0) {
        int run = 0;
        for (int d = 0; d < 128; ++d) { int v = hcur[d]; hcur[d] = run; run += v; }
    }
    __syncthreads();
    {
        int slot = atomicAdd(&hcur[db], 1);
        nperm[g * N_ + slot] = (unsigned short)tid;
    }

    int pc = (mydeg + 1) & ~1;            // even-padded bin size
    startv[tid] = pc;
    __syncthreads();
    for (int off = 1; off < N_; off <<= 1) {
        tmpv[tid] = startv[tid] + (tid >= off ? startv[tid - off] : 0);
        __syncthreads();
        startv[tid] = tmpv[tid];
        __syncthreads();
    }

    int excl = startv[tid] - pc;
    cursor[tid] = excl;
    gstart[g * (N_ + 1) + tid] = excl;
    if (tid == 511) gstart[g * (N_ + 1) + N_] = startv[511];
    disd[nb + tid] = 1.0 / sqrt((double)(mydeg + 1));
    __syncthreads();

    for (int e = tid; e < EG_; e += 512) {
        int d = ds[e] - nb;
        int slot = atomicAdd(&cursor[d], 1);
        binE[slot] = (unsigned short)e;
    }
    __syncthreads();

    {   // canonicalize own bin: insertion sort by edge id (original order)
        int n = mydeg;
        for (int i = 1; i < n; ++i) {
            unsigned short key = binE[excl + i];
            int j = i - 1;
            while (j >= 0 && binE[excl + j] > key) {
                binE[excl + j + 1] = binE[excl + j];
                --j;
            }
            binE[excl + j + 1] = key;
        }
    }
    __syncthreads();

    for (int i = tid; i < EGP; i += 512) {
        unsigned short e = binE[i];
        srcl[(size_t)g * EGP + i] =
            (e == 0xFFFF) ? (unsigned short)N_ : (unsigned short)(ss[e] - nb);
    }
}

// ---------------- matmul (layer 1): h = x @ W0, fp64 acc -------------------
template <int CI>
__global__ __launch_bounds__(256) void mm_kernel(const float* __restrict__ xin,
                                                 const float* __restrict__ W,
                                                 double* __restrict__ h) {
    __shared__ float sx[64][CI + 4];      // CI=128: 33.8 KB
    __shared__ float sWt[HID_][CI + 5];   // transposed, pitch 133
    int tid = threadIdx.x;
    for (int i = tid; i < CI * HID_; i += 256) {
        int c = i / HID_, o = i % HID_;
        sWt[o][c] = W[i];
    }
    size_t base = (size_t)blockIdx.x * 64;
    const float4* xsrc = (const float4*)(xin + base * CI);
    for (int i = tid; i < 64 * CI / 4; i += 256) {
        int row = i / (CI / 4), col = (i % (CI / 4)) * 4;
        *(float4*)&sx[row][col] = xsrc[i];
    }
    __syncthreads();

    int o2 = tid & 15, q = tid >> 4;     // 16 q-groups x 4 nodes
    int n0 = q * 4;
    double acc[4][2];
#pragma unroll
    for (int j = 0; j < 4; ++j) { acc[j][0] = 0.0; acc[j][1] = 0.0; }

    for (int c = 0; c < CI; c += 4) {
        float4 wa = *(const float4*)&sWt[2 * o2][c];
        float4 wb = *(const float4*)&sWt[2 * o2 + 1][c];
        double w0a = (double)wa.x, w1a = (double)wa.y,
               w2a = (double)wa.z, w3a = (double)wa.w;
        double w0b = (double)wb.x, w1b = (double)wb.y,
               w2b = (double)wb.z, w3b = (double)wb.w;
#pragma unroll
        for (int j = 0; j < 4; ++j) {
            float4 v = *(const float4*)&sx[n0 + j][c];
            double vx = (double)v.x, vy = (double)v.y,
                   vz = (double)v.z, vw = (double)v.w;
            acc[j][0] = fma(vx, w0a, acc[j][0]);
            acc[j][0] = fma(vy, w1a, acc[j][0]);
            acc[j][0] = fma(vz, w2a, acc[j][0]);
            acc[j][0] = fma(vw, w3a, acc[j][0]);
            acc[j][1] = fma(vx, w0b, acc[j][1]);
            acc[j][1] = fma(vy, w1b, acc[j][1]);
            acc[j][1] = fma(vz, w2b, acc[j][1]);
            acc[j][1] = fma(vw, w3b, acc[j][1]);
        }
    }
    int stripe = o2 >> 3;
    // channels 2*o2 and 2*o2+1 are in the same stripe (2*o2 span 0..31)
    {
        int o = 2 * o2;
        int strp = o >> 3;
        int oc = o & 7;
#pragma unroll
        for (int j = 0; j < 4; ++j) {
            double2 val;
            val.x = acc[j][0];
            val.y = acc[j][1];
            *(double2*)&h[(((size_t)strp) * NN_ + base + n0 + j) * SW + oc] = val;
        }
    }
    (void)stripe;
}

// ---------------- aggregation (layer 1): reads h64, paired edges -----------
__global__ __launch_bounds__(512) void agg_kernel(const double* __restrict__ h,
                                                  const unsigned short* __restrict__ srcl,
                                                  const int* __restrict__ gstart,
                                                  const unsigned short* __restrict__ nperm,
                                                  const double* __restrict__ disd,
                                                  const float* __restrict__ bias,
                                                  float* __restrict__ xoutf) {
    __shared__ double hd2[SW * HP];            // 32.8 KB, channel-major
    __shared__ unsigned short ssrc[EGP];       // 17.4 KB
    __shared__ unsigned short sstart[N_ + 2];  // 1 KB
    __shared__ unsigned short sperm[N_];       // 1 KB
    int g, st, tid = threadIdx.x;
    decode_swz(blockIdx.x, g, st);
    size_t nbase = (size_t)g * N_;

    for (int i = tid; i < EGP; i += 512) ssrc[i] = srcl[(size_t)g * EGP + i];
    for (int i = tid; i <= N_; i += 512) sstart[i] = (unsigned short)gstart[g * (N_ + 1) + i];
    sperm[tid] = nperm[g * N_ + tid];
    __syncthreads();

    const double* hraw = h + ((size_t)st * NN_ + nbase) * SW;
    const double* dg = disd + nbase;
    for (int i = tid; i < N_ * SW; i += 512) {
        int s = i >> 3, oc = i & 7;
        hd2[oc * HP + s] = hraw[i] * dg[s];
    }
    if (tid < SW) hd2[tid * HP + N_] = -0.0;   // sentinel
    __syncthreads();

    int oc = tid & 7, grp = tid >> 3;   // 64 node-groups x 8 channels
    const double* hrow = hd2 + oc * HP;
    const unsigned int* ssrc32 = (const unsigned int*)ssrc;
    double b = (double)bias[st * SW + oc];

    int nn[8], e0h[8], e1h[8];
    double a[8];
    int mx = 0;
#pragma unroll
    for (int j = 0; j < 8; ++j) {
        int n = sperm[grp * 8 + j];
        nn[j] = n;
        e0h[j] = sstart[n] >> 1;
        e1h[j] = sstart[n + 1] >> 1;
        a[j] = 0.0;
        int d = e1h[j] - e0h[j];
        mx = d > mx ? d : mx;
    }
    for (int t = 0; t < mx; ++t) {
#pragma unroll
        for (int j = 0; j < 8; ++j) {
            int idx = e0h[j] + t;
            if (idx < e1h[j]) {
                unsigned int pr = ssrc32[idx];
                a[j] += hrow[pr & 0xFFFFu];
                a[j] += hrow[pr >> 16];
            }
        }
    }
#pragma unroll
    for (int j = 0; j < 8; ++j) {
        int n = nn[j];
        double dn = dg[n];
        double v = a[j] * dn + hrow[n] * dn + b;
        xoutf[(nbase + n) * HID_ + st * SW + oc] = tanhf((float)v);
    }
}

// ---------------- fused layer-2: in-block mm (x1f@W1 slice) + aggregation --
__global__ __launch_bounds__(512) void agg_mm_kernel(
        const float* __restrict__ xin,    // x1f
        const float* __restrict__ W,      // W1 [32][32]
        const unsigned short* __restrict__ srcl,
        const int* __restrict__ gstart,
        const unsigned short* __restrict__ nperm,
        const double* __restrict__ disd,
        const float* __restrict__ bias,
        float* __restrict__ xoutf) {
    __shared__ double hd2[SW * HP];            // 32.8 KB
    __shared__ unsigned short ssrc[EGP];       // 17.4 KB
    __shared__ unsigned short sstart[N_ + 2];  // 1 KB
    __shared__ double sWd[HID_ * SW];          // fp64 W slice, 2 KB
    int g, st, tid = threadIdx.x;
    decode_swz(blockIdx.x, g, st);
    size_t nbase = (size_t)g * N_;

    for (int i = tid; i < EGP; i += 512) ssrc[i] = srcl[(size_t)g * EGP + i];
    for (int i = tid; i <= N_; i += 512) sstart[i] = (unsigned short)gstart[g * (N_ + 1) + i];
    if (tid < HID_ * SW) {
        int c = tid >> 3, oc = tid & 7;
        sWd[tid] = (double)W[c * HID_ + st * SW + oc];
    }
    __syncthreads();

    const double* dg = disd + nbase;
    {   // in-block mm: node s = tid; c-ascending fma chain (bit-identical)
        int s = tid;
        const float4* xr4 = (const float4*)(xin + (nbase + s) * HID_);
        float xrow[HID_];
#pragma unroll
        for (int q = 0; q < HID_ / 4; ++q) {
            float4 v = xr4[q];
            xrow[q * 4 + 0] = v.x;
            xrow[q * 4 + 1] = v.y;
            xrow[q * 4 + 2] = v.z;
            xrow[q * 4 + 3] = v.w;
        }
        double a[SW];
#pragma unroll
        for (int oc = 0; oc < SW; ++oc) a[oc] = 0.0;
#pragma unroll
        for (int c = 0; c < HID_; ++c) {
            double xv = (double)xrow[c];
#pragma unroll
            for (int oc = 0; oc < SW; ++oc)
                a[oc] = fma(xv, sWd[c * SW + oc], a[oc]);
        }
        double ds = dg[s];
#pragma unroll
        for (int oc = 0; oc < SW; ++oc)
            hd2[oc * HP + s] = a[oc] * ds;
    }
    if (tid < SW) hd2[tid * HP + N_] = -0.0;   // sentinel
    __syncthreads();

    int oc = tid & 7, grp = tid >> 3;   // 64 node-groups x 8 channels
    const double* hrow = hd2 + oc * HP;
    const unsigned int* ssrc32 = (const unsigned int*)ssrc;
    double b = (double)bias[st * SW + oc];

    int nn[8], e0h[8], e1h[8];
    double a[8];
    int mx = 0;
#pragma unroll
    for (int j = 0; j < 8; ++j) {
        int n = nperm[g * N_ + grp * 8 + j];
        nn[j] = n;
        e0h[j] = sstart[n] >> 1;
        e1h[j] = sstart[n + 1] >> 1;
        a[j] = 0.0;
        int d = e1h[j] - e0h[j];
        mx = d > mx ? d : mx;
    }
    for (int t = 0; t < mx; ++t) {
#pragma unroll
        for (int j = 0; j < 8; ++j) {
            int idx = e0h[j] + t;
            if (idx < e1h[j]) {
                unsigned int pr = ssrc32[idx];
                a[j] += hrow[pr & 0xFFFFu];
                a[j] += hrow[pr >> 16];
            }
        }
    }
#pragma unroll
    for (int j = 0; j < 8; ++j) {
        int n = nn[j];
        double dn = dg[n];
        double v = a[j] * dn + hrow[n] * dn + b;
        xoutf[(nbase + n) * HID_ + st * SW + oc] = tanhf((float)v);
    }
}

// ---------------- fused layer-3 + head (one block per graph, 512 thr) ------
__global__ __launch_bounds__(512) void gcn3_head_kernel(
        const float* __restrict__ xin,      // x2f
        const float* __restrict__ W2,
        const float* __restrict__ b2,
        const unsigned short* __restrict__ srcl,
        const int* __restrict__ gstart,
        const double* __restrict__ disd,
        const float* __restrict__ x1,
        const float* __restrict__ x2,
        const float* __restrict__ c1w, const float* __restrict__ c1b,
        const float* __restrict__ c2w, const float* __restrict__ c2b,
        const float* __restrict__ l1w, const float* __restrict__ l1b,
        const float* __restrict__ l2w, const float* __restrict__ l2b,
        float* __restrict__ out) {
    __shared__ double h1[N_ + 1];
    __shared__ unsigned short ssrc[EGP];
    __shared__ int sstart[N_ + 1];
    __shared__ double sdis[N_ + 1];
    __shared__ float sv[N_];
    __shared__ int   topk[K_];
    __shared__ float pooled[K_][LAT_];
    __shared__ float c1[16][K_];
    __shared__ float mp[16][10];
    __shared__ float c2s[32 * 6];
    __shared__ float l1s[128];
    int g = blockIdx.x, tid = threadIdx.x;
    size_t nbase = (size_t)g * N_;

    for (int i = tid; i < EGP; i += 512) ssrc[i] = srcl[(size_t)g * EGP + i];
    for (int i = tid; i <= N_; i += 512) sstart[i] = gstart[g * (N_ + 1) + i];
    if (tid == 0) { h1[N_] = -0.0; sdis[N_] = 1.0; }   // sentinel term: -0.0
    if (tid < K_) topk[tid] = tid;                      // fallback init
    int n = tid;
    {
        double a = 0.0;
#pragma unroll
        for (int c = 0; c < HID_; ++c)
            a = fma((double)xin[(nbase + n) * HID_ + c], (double)W2[c], a);
        h1[n] = a;
        sdis[n] = disd[nbase + n];
    }
    __syncthreads();

    {
        int e0 = sstart[n], e1 = sstart[n + 1];
        double a = 0.0;
        for (int e = e0; e < e1; ++e) {
            int s = ssrc[e];
            a += h1[s] * sdis[s];
        }
        double dn = sdis[n];
        double v = a * dn + h1[n] * dn * dn + (double)b2[0];
        sv[n] = (float)tanh(v);   // fp32 rank key AND feature value
    }
    __syncthreads();

    {
        float v = sv[n];
        int rank = 0;
        for (int j = 0; j < N_; ++j) {
            float u = sv[j];
            float mag = fmaxf(fabsf(u), fabsf(v));
            bool tie = fabsf(u - v) <= EPS_REL * mag;
            bool beats = tie ? (j < n) : (u > v);
            rank += beats;
        }
        if (rank < K_) topk[rank] = n;
    }
    __syncthreads();

    for (int i = tid; i < K_ * LAT_; i += 512) {
        int k = i / LAT_, c = i % LAT_;
        int node = topk[k];
        float f;
        if (c < HID_)            f = x1[(nbase + node) * HID_ + c];
        else if (c < 2 * HID_)   f = x2[(nbase + node) * HID_ + (c - HID_)];
        else                     f = sv[node];
        pooled[k][c] = f;
    }
    __syncthreads();

    for (int i = tid; i < 16 * K_; i += 512) {
        int o = i / K_, k = i % K_;
        float acc = c1b[o];
        for (int c = 0; c < LAT_; ++c) acc += pooled[k][c] * c1w[o * LAT_ + c];
        c1[o][k] = fmaxf(acc, 0.f);
    }
    __syncthreads();

    for (int i = tid; i < 160; i += 512) {
        int o = i / 10, t = i % 10;
        mp[o][t] = fmaxf(c1[o][2 * t], c1[o][2 * t + 1]);
    }
    __syncthreads();

    for (int i = tid; i < 192; i += 512) {
        int o = i / 6, t = i % 6;
        float acc = c2b[o];
        for (int ic = 0; ic < 16; ++ic)
#pragma unroll
            for (int j = 0; j < 5; ++j)
                acc += mp[ic][t + j] * c2w[(o * 16 + ic) * 5 + j];
        c2s[o * 6 + t] = fmaxf(acc, 0.f);
    }
    __syncthreads();

    for (int i = tid; i < 128; i += 512) {
        float acc = l1b[i];
        for (int c = 0; c < 192; ++c) acc += c2s[c] * l1w[c * 128 + i];
        l1s[i] = fmaxf(acc, 0.f);
    }
    __syncthreads();

    for (int i = tid; i < 2; i += 512) {
        float acc = l2b[i];
        for (int c = 0; c < 128; ++c) acc += l1s[c] * l2w[c * 2 + i];
        out[g * 2 + i] = acc;
    }
}

extern "C" void kernel_launch(void* const* d_in, const int* in_sizes, int n_in,
                              void* d_out, int out_size, void* d_ws, size_t ws_size,
                              hipStream_t stream) {
    const float* x   = (const float*)d_in[0];
    const int*   ei  = (const int*)d_in[1];
    const float* W0  = (const float*)d_in[3];
    const float* b0  = (const float*)d_in[4];
    const float* W1  = (const float*)d_in[5];
    const float* b1  = (const float*)d_in[6];
    const float* W2  = (const float*)d_in[7];
    const float* b2  = (const float*)d_in[8];
    const float* c1w = (const float*)d_in[9];
    const float* c1b = (const float*)d_in[10];
    const float* c2w = (const float*)d_in[11];
    const float* c2b = (const float*)d_in[12];
    const float* l1w = (const float*)d_in[13];
    const float* l1b = (const float*)d_in[14];
    const float* l2w = (const float*)d_in[15];
    const float* l2b = (const float*)d_in[16];

    const int* src = ei;
    const int* dst = ei + (size_t)G_ * EG_;

    char* wsb = (char*)d_ws;
    double* h64  = (double*)wsb;                 wsb += (size_t)NN_ * HID_ * 8;     // 64 MiB (stripe-major)
    unsigned short* srcl = (unsigned short*)wsb; wsb += (size_t)G_ * EGP * 2;       // 8.5 MiB
    int* gstart = (int*)wsb;                     wsb += (size_t)G_ * (N_ + 1) * 4;  // 1 MiB
    unsigned short* nperm = (unsigned short*)wsb; wsb += (size_t)G_ * N_ * 2;       // 0.5 MiB
    double* disd = (double*)wsb;                 wsb += (size_t)NN_ * 8;            // 2 MiB
    float*  x1f  = (float*)wsb;                  wsb += (size_t)NN_ * HID_ * 4;     // 32 MiB
    float*  x2f  = (float*)wsb;                  wsb += (size_t)NN_ * HID_ * 4;     // 32 MiB

    csr2_kernel<<<G_, 512, 0, stream>>>(src, dst, srcl, gstart, nperm, disd);
    mm_kernel<CIN_><<<NN_ / 64, 256, 0, stream>>>(x, W0, h64);
    agg_kernel<<<G_ * NSTRIPE, 512, 0, stream>>>(h64, srcl, gstart, nperm, disd, b0, x1f);
    agg_mm_kernel<<<G_ * NSTRIPE, 512, 0, stream>>>(x1f, W1, srcl, gstart, nperm, disd, b1, x2f);
    gcn3_head_kernel<<<G_, 512, 0, stream>>>(x2f, W2, b2, srcl, gstart, disd,
                                             x1f, x2f, c1w, c1b, c2w, c2b,
                                             l1w, l1b, l2w, l2b, (float*)d_out);
}